// Round 3
// baseline (287.286 us; speedup 1.0000x reference)
//
#include <hip/hip_runtime.h>
#include <hip/hip_bf16.h>
#include <stdint.h>

#define ALPHA_ 0.2f
#define EPS_   1e-6f

typedef __attribute__((ext_vector_type(8))) short  short8;
typedef __attribute__((ext_vector_type(4))) float  float4v;

union U8 { short8 s8; unsigned int u[4]; };

static __device__ __forceinline__ unsigned short f2bf(float x) {
    union { float f; unsigned int u; } c; c.f = x;
    return (unsigned short)((c.u + 0x7fffu + ((c.u >> 16) & 1u)) >> 16);
}

// ---------------- K0: WT[f][d] = bf16(W[d][f]) ------------------------------
__global__ __launch_bounds__(256) void k_wt(const float* __restrict__ W,
                                            unsigned short* __restrict__ WT) {
    const int t  = threadIdx.x;
    const int f  = blockIdx.x * 8 + (t >> 5);
    const int d0 = (t & 31) * 8;
    unsigned short v[8];
#pragma unroll
    for (int k = 0; k < 8; ++k) v[k] = f2bf(W[(d0 + k) * 256 + f]);
    uint4 o;
    o.x = (unsigned)v[0] | ((unsigned)v[1] << 16);
    o.y = (unsigned)v[2] | ((unsigned)v[3] << 16);
    o.z = (unsigned)v[4] | ((unsigned)v[5] << 16);
    o.w = (unsigned)v[6] | ((unsigned)v[7] << 16);
    *(uint4*)(WT + f * 256 + d0) = o;
}

// ---------------- K1: MFMA Wh = h@W; fused s1/s2; LDS-transposed WhT --------
__global__ __launch_bounds__(256) void k_wh(const float* __restrict__ h,
                                            const unsigned short* __restrict__ WT,
                                            const float* __restrict__ a,
                                            unsigned short* __restrict__ WhT,
                                            float* __restrict__ s1g,
                                            float* __restrict__ s2g) {
    __shared__ __align__(16) unsigned short A_lds[32][264];   // pad 256->264
    __shared__ __align__(16) unsigned short T_lds[256][40];   // [f][j] pad 32->40
    __shared__ float s1p[32], s2p[32];
    const int t    = threadIdx.x;
    const int lane = t & 63;
    const int wv   = t >> 6;
    const int m    = lane & 15;
    const int quad = lane >> 4;
    const int r0   = blockIdx.x * 32;     // 512 blocks
    const int b    = r0 >> 11;
    const int j0   = r0 & 2047;

    if (t < 32) { s1p[t] = 0.f; s2p[t] = 0.f; }

    // stage h tile fp32 -> bf16 LDS (A layout [row][d], coalesced float4)
#pragma unroll
    for (int k = 0; k < 8; ++k) {
        const int flat = t + k * 256;
        const int r  = flat >> 6;
        const int d4 = flat & 63;
        float4v hv = *(const float4v*)(h + (size_t)(r0 + r) * 256 + d4 * 4);
        uint2 pk;
        pk.x = (unsigned)f2bf(hv.x) | ((unsigned)f2bf(hv.y) << 16);
        pk.y = (unsigned)f2bf(hv.z) | ((unsigned)f2bf(hv.w) << 16);
        *(uint2*)&A_lds[r][d4 * 4] = pk;
    }
    __syncthreads();

    const int fbase = wv * 64;
    float4v acc[2][4];
#pragma unroll
    for (int it = 0; it < 2; ++it)
#pragma unroll
        for (int ft = 0; ft < 4; ++ft)
#pragma unroll
            for (int r = 0; r < 4; ++r) acc[it][ft][r] = 0.f;

    const unsigned short* wtp = WT + (size_t)(fbase + m) * 256 + quad * 8;
    short8 bcur[4], bnxt[4];
#pragma unroll
    for (int ft = 0; ft < 4; ++ft) bcur[ft] = *(const short8*)(wtp + ft * 16 * 256);

#pragma unroll
    for (int kc = 0; kc < 8; ++kc) {
        const int kn = (kc + 1) & 7;
#pragma unroll
        for (int ft = 0; ft < 4; ++ft)
            bnxt[ft] = *(const short8*)(wtp + ft * 16 * 256 + kn * 32);
        short8 af0 = *(const short8*)&A_lds[m][kc * 32 + quad * 8];
        short8 af1 = *(const short8*)&A_lds[16 + m][kc * 32 + quad * 8];
#pragma unroll
        for (int ft = 0; ft < 4; ++ft) {
            acc[0][ft] = __builtin_amdgcn_mfma_f32_16x16x32_bf16(af0, bcur[ft], acc[0][ft], 0, 0, 0);
            acc[1][ft] = __builtin_amdgcn_mfma_f32_16x16x32_bf16(af1, bcur[ft], acc[1][ft], 0, 0, 0);
        }
#pragma unroll
        for (int ft = 0; ft < 4; ++ft) bcur[ft] = bnxt[ft];
    }

    // fused s1/s2
    float a1v[4], a2v[4];
#pragma unroll
    for (int ft = 0; ft < 4; ++ft) {
        a1v[ft] = a[fbase + ft * 16 + m];
        a2v[ft] = a[256 + fbase + ft * 16 + m];
    }
#pragma unroll
    for (int it = 0; it < 2; ++it) {
#pragma unroll
        for (int reg = 0; reg < 4; ++reg) {
            float v1 = 0.f, v2 = 0.f;
#pragma unroll
            for (int ft = 0; ft < 4; ++ft) {
                const float c = acc[it][ft][reg];
                v1 = fmaf(c, a1v[ft], v1);
                v2 = fmaf(c, a2v[ft], v2);
            }
            v1 += __shfl_xor(v1, 1); v2 += __shfl_xor(v2, 1);
            v1 += __shfl_xor(v1, 2); v2 += __shfl_xor(v2, 2);
            v1 += __shfl_xor(v1, 4); v2 += __shfl_xor(v2, 4);
            v1 += __shfl_xor(v1, 8); v2 += __shfl_xor(v2, 8);
            if (m == 0) {
                const int row = it * 16 + quad * 4 + reg;
                atomicAdd(&s1p[row], v1);
                atomicAdd(&s2p[row], v2);
            }
        }
    }

    // WhT via LDS transpose: lane writes its C-fragment elems to T_lds[f][j]
    // (rows f in [wv*64, wv*64+64) -> same-wave readback, no barrier needed)
#pragma unroll
    for (int it = 0; it < 2; ++it)
#pragma unroll
        for (int ft = 0; ft < 4; ++ft)
#pragma unroll
            for (int reg = 0; reg < 4; ++reg)
                T_lds[fbase + ft * 16 + m][it * 16 + quad * 4 + reg] =
                    f2bf(acc[it][ft][reg]);

    // thread t owns f=t: 64 B contiguous j -> coalesced 4x16B global stores
    {
        uint4 o0 = *(const uint4*)&T_lds[t][0];
        uint4 o1 = *(const uint4*)&T_lds[t][8];
        uint4 o2 = *(const uint4*)&T_lds[t][16];
        uint4 o3 = *(const uint4*)&T_lds[t][24];
        unsigned short* wto = WhT + ((size_t)(b * 256 + t) * 2048) + j0;
        *(uint4*)(wto + 0)  = o0;
        *(uint4*)(wto + 8)  = o1;
        *(uint4*)(wto + 16) = o2;
        *(uint4*)(wto + 24) = o3;
    }

    __syncthreads();
    if (t < 32) {
        s1g[(size_t)b * 2048 + j0 + t] = s1p[t];
        s2g[(size_t)b * 2048 + j0 + t] = s2p[t];
    }
}

// ---------------- K3: fused softmax aggregation — wave-private, barrier-free
// 256 blocks x 256 thr. Wave = 32 i-rows x 128 f, all j. p computed in-regs
// (A-frag layout A[m=lane&15][k=quad*8+idx]); adj prefetch 2 steps, B 1 step.
static __device__ __forceinline__ uint2 pquad(float4v av, float4v s2v,
                                              float s1, float& rs) {
    float e0 = s1 + s2v.x, e1 = s1 + s2v.y, e2 = s1 + s2v.z, e3 = s1 + s2v.w;
    e0 = fmaxf(e0, ALPHA_ * e0); e1 = fmaxf(e1, ALPHA_ * e1);
    e2 = fmaxf(e2, ALPHA_ * e2); e3 = fmaxf(e3, ALPHA_ * e3);
    const float p0 = (av.x + EPS_) * __expf(e0);
    const float p1 = (av.y + EPS_) * __expf(e1);
    const float p2 = (av.z + EPS_) * __expf(e2);
    const float p3 = (av.w + EPS_) * __expf(e3);
    rs += (p0 + p1) + (p2 + p3);
    uint2 r;
    r.x = (unsigned)f2bf(p0) | ((unsigned)f2bf(p1) << 16);
    r.y = (unsigned)f2bf(p2) | ((unsigned)f2bf(p3) << 16);
    return r;
}

__global__ __launch_bounds__(256, 1) void k_attn(const float* __restrict__ adj,
                                                 const unsigned short* __restrict__ WhT,
                                                 const float* __restrict__ s1g,
                                                 const float* __restrict__ s2g,
                                                 float* __restrict__ out) {
    const int t     = threadIdx.x;
    const int lane  = t & 63;
    const int wv    = t >> 6;
    const int m     = lane & 15;
    const int quad  = lane >> 4;
    const int fhalf = wv & 1;
    const int itile = blockIdx.x * 2 + (wv >> 1);   // 512 itiles x 2 fhalves
    const int b     = itile >> 6;
    const int i0    = (itile & 63) * 32;

    const float* adjp0 = adj + (size_t)(b * 2048 + i0 + m) * 2048 + quad * 8;
    const float* adjp1 = adjp0 + 16 * 2048;
    const float* s2p   = s2g + (size_t)b * 2048 + quad * 8;
    const float  s1v0  = s1g[(size_t)b * 2048 + i0 + m];
    const float  s1v1  = s1g[(size_t)b * 2048 + i0 + 16 + m];

    const unsigned short* wtp =
        WhT + (size_t)(b * 256 + fhalf * 128 + m) * 2048 + quad * 8;

    float4v acc[2][8];
#pragma unroll
    for (int it = 0; it < 2; ++it)
#pragma unroll
        for (int ft = 0; ft < 8; ++ft)
#pragma unroll
            for (int r = 0; r < 4; ++r) acc[it][ft][r] = 0.f;

    float4v a0buf[2][2], a1buf[2][2], s2buf[2][2];
    short8  bb[2][8];
    float   rs0 = 0.f, rs1 = 0.f;

    // prologue: adj/s2 for steps 0,1; B for step 0
    a0buf[0][0] = *(const float4v*)(adjp0);      a0buf[0][1] = *(const float4v*)(adjp0 + 4);
    a1buf[0][0] = *(const float4v*)(adjp1);      a1buf[0][1] = *(const float4v*)(adjp1 + 4);
    a0buf[1][0] = *(const float4v*)(adjp0 + 32); a0buf[1][1] = *(const float4v*)(adjp0 + 36);
    a1buf[1][0] = *(const float4v*)(adjp1 + 32); a1buf[1][1] = *(const float4v*)(adjp1 + 36);
    s2buf[0][0] = *(const float4v*)(s2p);        s2buf[0][1] = *(const float4v*)(s2p + 4);
    s2buf[1][0] = *(const float4v*)(s2p + 32);   s2buf[1][1] = *(const float4v*)(s2p + 36);
#pragma unroll
    for (int ft = 0; ft < 8; ++ft)
        bb[0][ft] = *(const short8*)(wtp + (size_t)ft * 16 * 2048);

#define STEP_BODY(BUF, S)                                                        \
  {                                                                              \
    U8 af0u, af1u;                                                               \
    uint2 q00 = pquad(a0buf[BUF][0], s2buf[BUF][0], s1v0, rs0);                  \
    uint2 q01 = pquad(a0buf[BUF][1], s2buf[BUF][1], s1v0, rs0);                  \
    uint2 q10 = pquad(a1buf[BUF][0], s2buf[BUF][0], s1v1, rs1);                  \
    uint2 q11 = pquad(a1buf[BUF][1], s2buf[BUF][1], s1v1, rs1);                  \
    af0u.u[0] = q00.x; af0u.u[1] = q00.y; af0u.u[2] = q01.x; af0u.u[3] = q01.y;  \
    af1u.u[0] = q10.x; af1u.u[1] = q10.y; af1u.u[2] = q11.x; af1u.u[3] = q11.y;  \
    const int sp = ((S) + 2) & 63;                                               \
    a0buf[BUF][0] = *(const float4v*)(adjp0 + (size_t)sp * 32);                  \
    a0buf[BUF][1] = *(const float4v*)(adjp0 + (size_t)sp * 32 + 4);              \
    a1buf[BUF][0] = *(const float4v*)(adjp1 + (size_t)sp * 32);                  \
    a1buf[BUF][1] = *(const float4v*)(adjp1 + (size_t)sp * 32 + 4);              \
    s2buf[BUF][0] = *(const float4v*)(s2p + sp * 32);                            \
    s2buf[BUF][1] = *(const float4v*)(s2p + sp * 32 + 4);                        \
    const int sb = ((S) + 1) & 63;                                               \
    _Pragma("unroll")                                                            \
    for (int ft = 0; ft < 8; ++ft)                                               \
      bb[(BUF) ^ 1][ft] = *(const short8*)(wtp + (size_t)ft * 16 * 2048 + sb * 32); \
    _Pragma("unroll")                                                            \
    for (int ft = 0; ft < 8; ++ft) {                                             \
      acc[0][ft] = __builtin_amdgcn_mfma_f32_16x16x32_bf16(af0u.s8, bb[BUF][ft], acc[0][ft], 0, 0, 0); \
      acc[1][ft] = __builtin_amdgcn_mfma_f32_16x16x32_bf16(af1u.s8, bb[BUF][ft], acc[1][ft], 0, 0, 0); \
    }                                                                            \
  }

    for (int s = 0; s < 64; s += 2) {
        STEP_BODY(0, s)
        STEP_BODY(1, s + 1)
    }
#undef STEP_BODY

    // rowsum: quads of same m hold disjoint j-slices; xor-16/32 completes sums
    rs0 += __shfl_xor(rs0, 16); rs0 += __shfl_xor(rs0, 32);
    rs1 += __shfl_xor(rs1, 16); rs1 += __shfl_xor(rs1, 32);

    // epilogue: C/D col = lane&15 (f), row = quad*4+reg (i)
#pragma unroll
    for (int reg = 0; reg < 4; ++reg) {
        const int row  = quad * 4 + reg;
        const float inv0 = 1.0f / __shfl(rs0, row);
        const float inv1 = 1.0f / __shfl(rs1, row);
#pragma unroll
        for (int ft = 0; ft < 8; ++ft) {
            const int f = fhalf * 128 + ft * 16 + m;
            out[(size_t)(b * 2048 + i0 + row) * 256 + f]      = acc[0][ft][reg] * inv0;
            out[(size_t)(b * 2048 + i0 + 16 + row) * 256 + f] = acc[1][ft][reg] * inv1;
        }
    }
}

extern "C" void kernel_launch(void* const* d_in, const int* in_sizes, int n_in,
                              void* d_out, int out_size, void* d_ws, size_t ws_size,
                              hipStream_t stream) {
    const float* h   = (const float*)d_in[0];   // (8,2048,256)
    const float* adj = (const float*)d_in[1];   // (8,2048,2048)
    const float* W   = (const float*)d_in[2];   // (256,256)
    const float* a   = (const float*)d_in[3];   // (512,1)
    float* out = (float*)d_out;                 // (8,2048,256)

    unsigned short* WhT = (unsigned short*)d_ws;                        // 8.4 MB
    unsigned short* WT  = (unsigned short*)((char*)d_ws + 8388608);     // 128 KB
    float*          s1  = (float*)((char*)d_ws + 8388608 + 131072);     // 64 KB
    float*          s2  = s1 + 16384;                                   // 64 KB

    k_wt  <<<dim3(32),  dim3(256), 0, stream>>>(W, WT);
    k_wh  <<<dim3(512), dim3(256), 0, stream>>>(h, WT, a, WhT, s1, s2);
    k_attn<<<dim3(256), dim3(256), 0, stream>>>(adj, WhT, s1, s2, out);
}